// Round 1
// baseline (3446.326 us; speedup 1.0000x reference)
//
#include <hip/hip_runtime.h>
#include <math.h>

// GCN forward: 3x GCNConv (128->4->4->2) + linear classifier (2->4).
// Norm factorization: msg_i = (h_i @ W) * dinv[i]; agg_d = sum_{e:dst=d} msg_src;
// h'_d = tanh((agg_d + msg_d) * dinv[d] + b)   [self-loop = +msg_d term]

__global__ void k_deg_init(int* __restrict__ deg, int n) {
    int i = blockIdx.x * blockDim.x + threadIdx.x;
    if (i < n) deg[i] = 1;  // self-loop contributes 1 to every node's in-degree
}

__global__ void k_deg(const int* __restrict__ dst, int* __restrict__ deg, int e) {
    int i = blockIdx.x * blockDim.x + threadIdx.x;
    if (i < e) atomicAdd(&deg[dst[i]], 1);
}

__global__ void k_dinv(const int* __restrict__ deg, float* __restrict__ dinv, int n) {
    int i = blockIdx.x * blockDim.x + threadIdx.x;
    if (i < n) dinv[i] = 1.0f / sqrtf((float)deg[i]);  // deg >= 1 always (self-loop)
}

__global__ void k_zero(float* __restrict__ p, int count) {
    int i = blockIdx.x * blockDim.x + threadIdx.x;
    if (i < count) p[i] = 0.0f;
}

// Layer 1 GEMV: one wave (64 lanes) per node. Lane l loads x[node][2l:2l+2]
// (coalesced 512B/wave) and the matching 2 rows of W1; butterfly-reduce 4 dots.
__global__ void k_mm1(const float* __restrict__ x, const float* __restrict__ W,
                      const float* __restrict__ dinv, float* __restrict__ hs, int n) {
    int gid = blockIdx.x * blockDim.x + threadIdx.x;
    int node = gid >> 6;
    int lane = threadIdx.x & 63;
    if (node >= n) return;
    const float2 xv = *reinterpret_cast<const float2*>(x + (size_t)node * 128 + lane * 2);
    const float4 w0 = *reinterpret_cast<const float4*>(W + (lane * 2) * 4);
    const float4 w1 = *reinterpret_cast<const float4*>(W + (lane * 2 + 1) * 4);
    float a0 = xv.x * w0.x + xv.y * w1.x;
    float a1 = xv.x * w0.y + xv.y * w1.y;
    float a2 = xv.x * w0.z + xv.y * w1.z;
    float a3 = xv.x * w0.w + xv.y * w1.w;
#pragma unroll
    for (int m = 32; m >= 1; m >>= 1) {
        a0 += __shfl_xor(a0, m);
        a1 += __shfl_xor(a1, m);
        a2 += __shfl_xor(a2, m);
        a3 += __shfl_xor(a3, m);
    }
    if (lane == 0) {
        float di = dinv[node];
        *reinterpret_cast<float4*>(hs + (size_t)node * 4) =
            make_float4(a0 * di, a1 * di, a2 * di, a3 * di);
    }
}

__global__ void k_scatter4(const int* __restrict__ src, const int* __restrict__ dst,
                           const float* __restrict__ hs, float* __restrict__ agg, int e) {
    int i = blockIdx.x * blockDim.x + threadIdx.x;
    if (i >= e) return;
    int s = src[i], d = dst[i];
    float4 v = *reinterpret_cast<const float4*>(hs + (size_t)s * 4);
    atomicAdd(&agg[(size_t)d * 4 + 0], v.x);
    atomicAdd(&agg[(size_t)d * 4 + 1], v.y);
    atomicAdd(&agg[(size_t)d * 4 + 2], v.z);
    atomicAdd(&agg[(size_t)d * 4 + 3], v.w);
}

__global__ void k_scatter2(const int* __restrict__ src, const int* __restrict__ dst,
                           const float* __restrict__ hs, float* __restrict__ agg, int e) {
    int i = blockIdx.x * blockDim.x + threadIdx.x;
    if (i >= e) return;
    int s = src[i], d = dst[i];
    float2 v = *reinterpret_cast<const float2*>(hs + (size_t)s * 2);
    atomicAdd(&agg[(size_t)d * 2 + 0], v.x);
    atomicAdd(&agg[(size_t)d * 2 + 1], v.y);
}

// Finalize layer with FIN=4: h = tanh((agg+hs)*dinv + b); hsn = (h @ Wn)*dinv.
template <int FOUT>
__global__ void k_fin4(const float* __restrict__ agg, const float* __restrict__ hs,
                       const float* __restrict__ dinv, const float* __restrict__ b,
                       const float* __restrict__ Wn, float* __restrict__ hsn, int n) {
    int i = blockIdx.x * blockDim.x + threadIdx.x;
    if (i >= n) return;
    float4 a = *reinterpret_cast<const float4*>(agg + (size_t)i * 4);
    float4 s = *reinterpret_cast<const float4*>(hs + (size_t)i * 4);
    float di = dinv[i];
    float h0 = tanhf((a.x + s.x) * di + b[0]);
    float h1 = tanhf((a.y + s.y) * di + b[1]);
    float h2 = tanhf((a.z + s.z) * di + b[2]);
    float h3 = tanhf((a.w + s.w) * di + b[3]);
    float o[FOUT];
#pragma unroll
    for (int j = 0; j < FOUT; j++) {
        o[j] = (h0 * Wn[0 * FOUT + j] + h1 * Wn[1 * FOUT + j] +
                h2 * Wn[2 * FOUT + j] + h3 * Wn[3 * FOUT + j]) * di;
    }
    if constexpr (FOUT == 4) {
        *reinterpret_cast<float4*>(hsn + (size_t)i * 4) = make_float4(o[0], o[1], o[2], o[3]);
    } else {
        *reinterpret_cast<float2*>(hsn + (size_t)i * 2) = make_float2(o[0], o[1]);
    }
}

// Final layer: h3 = tanh((agg+hs)*dinv + b3) [N,2] -> d_out[N*4..]; out = h3@Wc+bc -> d_out[0..]
__global__ void k_fin3(const float* __restrict__ agg, const float* __restrict__ hs,
                       const float* __restrict__ dinv, const float* __restrict__ b3,
                       const float* __restrict__ Wc, const float* __restrict__ bc,
                       float* __restrict__ out, float* __restrict__ hout, int n) {
    int i = blockIdx.x * blockDim.x + threadIdx.x;
    if (i >= n) return;
    float2 a = *reinterpret_cast<const float2*>(agg + (size_t)i * 2);
    float2 s = *reinterpret_cast<const float2*>(hs + (size_t)i * 2);
    float di = dinv[i];
    float h0 = tanhf((a.x + s.x) * di + b3[0]);
    float h1 = tanhf((a.y + s.y) * di + b3[1]);
    *reinterpret_cast<float2*>(hout + (size_t)i * 2) = make_float2(h0, h1);
    float4 o;
    o.x = h0 * Wc[0] + h1 * Wc[4] + bc[0];
    o.y = h0 * Wc[1] + h1 * Wc[5] + bc[1];
    o.z = h0 * Wc[2] + h1 * Wc[6] + bc[2];
    o.w = h0 * Wc[3] + h1 * Wc[7] + bc[3];
    *reinterpret_cast<float4*>(out + (size_t)i * 4) = o;
}

extern "C" void kernel_launch(void* const* d_in, const int* in_sizes, int n_in,
                              void* d_out, int out_size, void* d_ws, size_t ws_size,
                              hipStream_t stream) {
    const float* x  = (const float*)d_in[0];
    const int*  ei  = (const int*)d_in[1];
    const float* W1 = (const float*)d_in[2];
    const float* b1 = (const float*)d_in[3];
    const float* W2 = (const float*)d_in[4];
    const float* b2 = (const float*)d_in[5];
    const float* W3 = (const float*)d_in[6];
    const float* b3 = (const float*)d_in[7];
    const float* Wc = (const float*)d_in[8];
    const float* bc = (const float*)d_in[9];

    const int n = in_sizes[0] / 128;
    const int e = in_sizes[1] / 2;
    const int* src = ei;
    const int* dst = ei + e;

    char* ws = (char*)d_ws;
    float* dinv = (float*)(ws + 0);                       // n floats   (0.4 MB)
    float* hsA  = (float*)(ws + (size_t)1 * 1024 * 1024); // n*4 floats (1.6 MB)
    float* hsB  = (float*)(ws + (size_t)3 * 1024 * 1024); // n*4 floats (1.6 MB)
    float* agg  = (float*)(ws + (size_t)5 * 1024 * 1024); // n*4 floats (1.6 MB)
    int*   deg  = (int*)agg;                              // aliased: used before agg

    float* out  = (float*)d_out;
    float* hout = out + (size_t)n * 4;

    const int nb = (n + 255) / 256;
    const int eb = (e + 255) / 256;
    const int zb4 = (n * 4 + 255) / 256;

    // degree + dinv
    k_deg_init<<<nb, 256, 0, stream>>>(deg, n);
    k_deg<<<eb, 256, 0, stream>>>(dst, deg, e);
    k_dinv<<<nb, 256, 0, stream>>>(deg, dinv, n);

    // layer 1: hsA = (x @ W1) * dinv
    k_mm1<<<(n + 3) / 4, 256, 0, stream>>>(x, W1, dinv, hsA, n);

    // layer 1 agg + finalize (fuses layer-2 matmul): hsB = (tanh(...) @ W2) * dinv
    k_zero<<<zb4, 256, 0, stream>>>(agg, n * 4);
    k_scatter4<<<eb, 256, 0, stream>>>(src, dst, hsA, agg, e);
    k_fin4<4><<<nb, 256, 0, stream>>>(agg, hsA, dinv, b1, W2, hsB, n);

    // layer 2 agg + finalize (fuses layer-3 matmul): hsA = (tanh(...) @ W3) * dinv  [n*2]
    k_zero<<<zb4, 256, 0, stream>>>(agg, n * 4);
    k_scatter4<<<eb, 256, 0, stream>>>(src, dst, hsB, agg, e);
    k_fin4<2><<<nb, 256, 0, stream>>>(agg, hsB, dinv, b2, W3, hsA, n);

    // layer 3 agg + finalize (fuses classifier): out + hout
    k_zero<<<zb4, 256, 0, stream>>>(agg, n * 4);
    k_scatter2<<<eb, 256, 0, stream>>>(src, dst, hsA, agg, e);
    k_fin3<<<nb, 256, 0, stream>>>(agg, hsA, dinv, b3, Wc, bc, out, hout, n);

    (void)n_in; (void)out_size; (void)ws_size;
}

// Round 2
// 1198.095 us; speedup vs baseline: 2.8765x; 2.8765x over previous
//
#include <hip/hip_runtime.h>
#include <math.h>

// GCN forward: 3x GCNConv (128->4->4->2) + classifier (2->4).
// Strategy: factorized norm (msg_i = (h_i@W)*dinv[i]), CSR-by-dst build once
// per call, then per-layer GATHER (no f32 atomics) fused with finalize.

__global__ void k_zero_i(int* __restrict__ p, int count) {
    int i = blockIdx.x * blockDim.x + threadIdx.x;
    if (i < count) p[i] = 0;
}

__global__ void k_deg(const int* __restrict__ dst, int* __restrict__ deg, int e) {
    int i = blockIdx.x * blockDim.x + threadIdx.x;
    if (i < e) atomicAdd(&deg[dst[i]], 1);
}

__global__ void k_dinv(const int* __restrict__ deg, float* __restrict__ dinv, int n) {
    int i = blockIdx.x * blockDim.x + threadIdx.x;
    if (i < n) dinv[i] = 1.0f / sqrtf((float)(deg[i] + 1));  // +1 self-loop
}

// Single-block exclusive scan of deg[0..n) -> rowoff (and cursor copy).
__global__ void k_scan(const int* __restrict__ deg, int* __restrict__ rowoff,
                       int* __restrict__ cursor, int n) {
    __shared__ int part[1024];
    const int t = threadIdx.x;
    const int C = (n + 1023) / 1024;
    const int lo = t * C, hi = min(lo + C, n);
    int s = 0;
    for (int i = lo; i < hi; i++) s += deg[i];
    part[t] = s;
    __syncthreads();
#pragma unroll
    for (int off = 1; off < 1024; off <<= 1) {
        int u = (t >= off) ? part[t - off] : 0;
        __syncthreads();
        part[t] += u;
        __syncthreads();
    }
    int run = part[t] - s;  // exclusive base for this chunk
    for (int i = lo; i < hi; i++) {
        rowoff[i] = run;
        cursor[i] = run;
        run += deg[i];
    }
    if (t == 1023) rowoff[n] = run;
}

__global__ void k_fill(const int* __restrict__ src, const int* __restrict__ dst,
                       int* __restrict__ cursor, int* __restrict__ csr, int e) {
    int i = blockIdx.x * blockDim.x + threadIdx.x;
    if (i >= e) return;
    int d = dst[i];
    int p = atomicAdd(&cursor[d], 1);
    csr[p] = src[i];
}

// Layer 1 GEMV: one wave per node. Lane l loads x[node][2l:2l+2] + 2 rows of W1.
__global__ void k_mm1(const float* __restrict__ x, const float* __restrict__ W,
                      const float* __restrict__ dinv, float* __restrict__ hs, int n) {
    int gid = blockIdx.x * blockDim.x + threadIdx.x;
    int node = gid >> 6;
    int lane = threadIdx.x & 63;
    if (node >= n) return;
    const float2 xv = *reinterpret_cast<const float2*>(x + (size_t)node * 128 + lane * 2);
    const float4 w0 = *reinterpret_cast<const float4*>(W + (lane * 2) * 4);
    const float4 w1 = *reinterpret_cast<const float4*>(W + (lane * 2 + 1) * 4);
    float a0 = xv.x * w0.x + xv.y * w1.x;
    float a1 = xv.x * w0.y + xv.y * w1.y;
    float a2 = xv.x * w0.z + xv.y * w1.z;
    float a3 = xv.x * w0.w + xv.y * w1.w;
#pragma unroll
    for (int m = 32; m >= 1; m >>= 1) {
        a0 += __shfl_xor(a0, m);
        a1 += __shfl_xor(a1, m);
        a2 += __shfl_xor(a2, m);
        a3 += __shfl_xor(a3, m);
    }
    if (lane == 0) {
        float di = dinv[node];
        *reinterpret_cast<float4*>(hs + (size_t)node * 4) =
            make_float4(a0 * di, a1 * di, a2 * di, a3 * di);
    }
}

// Gather + finalize, hs entries are float4. One wave per node.
// h = tanh((sum_{e} hs[src] + hs[node]) * dinv + b); hsn = (h @ Wn) * dinv.
template <int FOUT>
__global__ void k_gath_fin4(const int* __restrict__ rowoff, const int* __restrict__ csr,
                            const float* __restrict__ hs, const float* __restrict__ dinv,
                            const float* __restrict__ b, const float* __restrict__ Wn,
                            float* __restrict__ hsn, int n) {
    int gid = blockIdx.x * blockDim.x + threadIdx.x;
    int node = gid >> 6;
    int lane = threadIdx.x & 63;
    if (node >= n) return;
    int start = rowoff[node], end = rowoff[node + 1];
    float a0 = 0.f, a1 = 0.f, a2 = 0.f, a3 = 0.f;
    for (int j = start + lane; j < end; j += 64) {
        int s = csr[j];
        float4 v = *reinterpret_cast<const float4*>(hs + (size_t)s * 4);
        a0 += v.x; a1 += v.y; a2 += v.z; a3 += v.w;
    }
#pragma unroll
    for (int m = 32; m >= 1; m >>= 1) {
        a0 += __shfl_xor(a0, m);
        a1 += __shfl_xor(a1, m);
        a2 += __shfl_xor(a2, m);
        a3 += __shfl_xor(a3, m);
    }
    if (lane == 0) {
        float4 s = *reinterpret_cast<const float4*>(hs + (size_t)node * 4);
        float di = dinv[node];
        float h0 = tanhf((a0 + s.x) * di + b[0]);
        float h1 = tanhf((a1 + s.y) * di + b[1]);
        float h2 = tanhf((a2 + s.z) * di + b[2]);
        float h3 = tanhf((a3 + s.w) * di + b[3]);
        float o[FOUT];
#pragma unroll
        for (int j = 0; j < FOUT; j++) {
            o[j] = (h0 * Wn[0 * FOUT + j] + h1 * Wn[1 * FOUT + j] +
                    h2 * Wn[2 * FOUT + j] + h3 * Wn[3 * FOUT + j]) * di;
        }
        if constexpr (FOUT == 4) {
            *reinterpret_cast<float4*>(hsn + (size_t)node * 4) =
                make_float4(o[0], o[1], o[2], o[3]);
        } else {
            *reinterpret_cast<float2*>(hsn + (size_t)node * 2) = make_float2(o[0], o[1]);
        }
    }
}

// Final layer: gather float2, h3 = tanh(...), out = h3@Wc + bc.
__global__ void k_gath_fin3(const int* __restrict__ rowoff, const int* __restrict__ csr,
                            const float* __restrict__ hs, const float* __restrict__ dinv,
                            const float* __restrict__ b3, const float* __restrict__ Wc,
                            const float* __restrict__ bc, float* __restrict__ out,
                            float* __restrict__ hout, int n) {
    int gid = blockIdx.x * blockDim.x + threadIdx.x;
    int node = gid >> 6;
    int lane = threadIdx.x & 63;
    if (node >= n) return;
    int start = rowoff[node], end = rowoff[node + 1];
    float a0 = 0.f, a1 = 0.f;
    for (int j = start + lane; j < end; j += 64) {
        int s = csr[j];
        float2 v = *reinterpret_cast<const float2*>(hs + (size_t)s * 2);
        a0 += v.x; a1 += v.y;
    }
#pragma unroll
    for (int m = 32; m >= 1; m >>= 1) {
        a0 += __shfl_xor(a0, m);
        a1 += __shfl_xor(a1, m);
    }
    if (lane == 0) {
        float2 s = *reinterpret_cast<const float2*>(hs + (size_t)node * 2);
        float di = dinv[node];
        float h0 = tanhf((a0 + s.x) * di + b3[0]);
        float h1 = tanhf((a1 + s.y) * di + b3[1]);
        *reinterpret_cast<float2*>(hout + (size_t)node * 2) = make_float2(h0, h1);
        float4 o;
        o.x = h0 * Wc[0] + h1 * Wc[4] + bc[0];
        o.y = h0 * Wc[1] + h1 * Wc[5] + bc[1];
        o.z = h0 * Wc[2] + h1 * Wc[6] + bc[2];
        o.w = h0 * Wc[3] + h1 * Wc[7] + bc[3];
        *reinterpret_cast<float4*>(out + (size_t)node * 4) = o;
    }
}

extern "C" void kernel_launch(void* const* d_in, const int* in_sizes, int n_in,
                              void* d_out, int out_size, void* d_ws, size_t ws_size,
                              hipStream_t stream) {
    const float* x  = (const float*)d_in[0];
    const int*  ei  = (const int*)d_in[1];
    const float* W1 = (const float*)d_in[2];
    const float* b1 = (const float*)d_in[3];
    const float* W2 = (const float*)d_in[4];
    const float* b2 = (const float*)d_in[5];
    const float* W3 = (const float*)d_in[6];
    const float* b3 = (const float*)d_in[7];
    const float* Wc = (const float*)d_in[8];
    const float* bc = (const float*)d_in[9];

    const int n = in_sizes[0] / 128;
    const int e = in_sizes[1] / 2;
    const int* src = ei;
    const int* dst = ei + e;

    const size_t MB = 1024 * 1024;
    char* ws = (char*)d_ws;
    float* dinv   = (float*)(ws + 0 * MB);   // n floats
    float* hsA    = (float*)(ws + 1 * MB);   // n*4 floats
    float* hsB    = (float*)(ws + 3 * MB);   // n*4 floats
    int*   deg    = (int*)  (ws + 5 * MB);   // n ints
    int*   rowoff = (int*)  (ws + 6 * MB);   // n+1 ints
    int*   cursor = (int*)  (ws + 7 * MB);   // n ints
    int*   csr    = (int*)  (ws + 8 * MB);   // e ints (25.6 MB)

    float* out  = (float*)d_out;
    float* hout = out + (size_t)n * 4;

    const int nb = (n + 255) / 256;
    const int eb = (e + 255) / 256;
    const int wb = (n + 3) / 4;  // wave-per-node kernels, 4 nodes per 256-block

    // CSR build (once; reused by all 3 layers)
    k_zero_i<<<nb, 256, 0, stream>>>(deg, n);
    k_deg<<<eb, 256, 0, stream>>>(dst, deg, e);
    k_dinv<<<nb, 256, 0, stream>>>(deg, dinv, n);
    k_scan<<<1, 1024, 0, stream>>>(deg, rowoff, cursor, n);
    k_fill<<<eb, 256, 0, stream>>>(src, dst, cursor, csr, e);

    // layer 1: hsA = (x @ W1) * dinv
    k_mm1<<<wb, 256, 0, stream>>>(x, W1, dinv, hsA, n);

    // layers 1..3: gather + finalize (fused next-layer matmul)
    k_gath_fin4<4><<<wb, 256, 0, stream>>>(rowoff, csr, hsA, dinv, b1, W2, hsB, n);
    k_gath_fin4<2><<<wb, 256, 0, stream>>>(rowoff, csr, hsB, dinv, b2, W3, hsA, n);
    k_gath_fin3<<<wb, 256, 0, stream>>>(rowoff, csr, hsA, dinv, b3, Wc, bc, out, hout, n);

    (void)n_in; (void)out_size; (void)ws_size;
}

// Round 3
// 832.396 us; speedup vs baseline: 4.1402x; 1.4393x over previous
//
#include <hip/hip_runtime.h>
#include <math.h>

// GCN forward: 3x GCNConv (128->4->4->2) + classifier (2->4).
// Edges partitioned once per call into 256-node dst-buckets (packed int:
// dl<<17|src). Per-layer aggregation = LDS-privatized atomicAdd per bucket,
// fused with finalize (tanh + next-layer matmul). Zero global atomics.

#define CHUNK 8192

// Pass A: per-block histogram of dst-buckets (bucket = dst>>8).
__global__ void k_hist(const int* __restrict__ dst, int* __restrict__ hbase,
                       int NB, int e) {
    __shared__ int hist[512];
    int g = blockIdx.x;
    for (int b = threadIdx.x; b < NB; b += 256) hist[b] = 0;
    __syncthreads();
    int i0 = g * CHUNK, i1 = min(i0 + CHUNK, e);
    for (int i = i0 + threadIdx.x; i < i1; i += 256)
        atomicAdd(&hist[dst[i] >> 8], 1);
    __syncthreads();
    for (int b = threadIdx.x; b < NB; b += 256)
        hbase[(size_t)g * NB + b] = hist[b];
}

// Scan: in-place column scan of hbase -> per-(block,bucket) global offsets;
// bstart[b] = start of bucket b in edge space.
__global__ void k_scan2(int* __restrict__ hbase, int* __restrict__ bstart,
                        int G, int NB, int e) {
    __shared__ int tot[512];
    int b = threadIdx.x;
    int run = 0;
    if (b < NB) {
        for (int g = 0; g < G; g++) {
            size_t idx = (size_t)g * NB + b;
            int t = hbase[idx];
            hbase[idx] = run;
            run += t;
        }
    }
    tot[b] = (b < NB) ? run : 0;
    __syncthreads();
#pragma unroll
    for (int off = 1; off < 512; off <<= 1) {
        int u = (b >= off) ? tot[b - off] : 0;
        __syncthreads();
        tot[b] += u;
        __syncthreads();
    }
    if (b < NB) {
        int excl = tot[b] - run;
        bstart[b] = excl;
        for (int g = 0; g < G; g++) hbase[(size_t)g * NB + b] += excl;
    }
    if (b == 0) bstart[NB] = e;
}

// Pass B: partition edges into buckets. Writes one packed int per edge into
// a per-(block,bucket) private contiguous run -> no line sharing, no global
// atomics. packed = (dst&255)<<17 | src   (src < 2^17).
__global__ void k_part(const int* __restrict__ src, const int* __restrict__ dst,
                       const int* __restrict__ base, int* __restrict__ packed,
                       int NB, int e) {
    __shared__ int cur[512];
    int g = blockIdx.x;
    for (int b = threadIdx.x; b < NB; b += 256) cur[b] = base[(size_t)g * NB + b];
    __syncthreads();
    int i0 = g * CHUNK, i1 = min(i0 + CHUNK, e);
    for (int i = i0 + threadIdx.x; i < i1; i += 256) {
        int d = dst[i];
        int s = src[i];
        int pos = atomicAdd(&cur[d >> 8], 1);
        packed[pos] = ((d & 255) << 17) | s;
    }
}

// Per-bucket degree histogram -> dinv (deg + 1 self-loop).
__global__ void k_deg2(const int* __restrict__ bstart, const int* __restrict__ packed,
                       float* __restrict__ dinv, int n) {
    __shared__ int cnt[256];
    int b = blockIdx.x;
    int tid = threadIdx.x;
    if (tid < 256) cnt[tid] = 0;
    __syncthreads();
    int j0 = bstart[b], j1 = bstart[b + 1];
    for (int j = j0 + tid; j < j1; j += 512)
        atomicAdd(&cnt[packed[j] >> 17], 1);
    __syncthreads();
    int node = (b << 8) + tid;
    if (tid < 256 && node < n)
        dinv[node] = 1.0f / sqrtf((float)(cnt[tid] + 1));
}

// Layer 1 GEMV: one wave per node. hs = (x @ W1) * dinv.
__global__ void k_mm1(const float* __restrict__ x, const float* __restrict__ W,
                      const float* __restrict__ dinv, float* __restrict__ hs, int n) {
    int gid = blockIdx.x * blockDim.x + threadIdx.x;
    int node = gid >> 6;
    int lane = threadIdx.x & 63;
    if (node >= n) return;
    const float2 xv = *reinterpret_cast<const float2*>(x + (size_t)node * 128 + lane * 2);
    const float4 w0 = *reinterpret_cast<const float4*>(W + (lane * 2) * 4);
    const float4 w1 = *reinterpret_cast<const float4*>(W + (lane * 2 + 1) * 4);
    float a0 = xv.x * w0.x + xv.y * w1.x;
    float a1 = xv.x * w0.y + xv.y * w1.y;
    float a2 = xv.x * w0.z + xv.y * w1.z;
    float a3 = xv.x * w0.w + xv.y * w1.w;
#pragma unroll
    for (int m = 32; m >= 1; m >>= 1) {
        a0 += __shfl_xor(a0, m);
        a1 += __shfl_xor(a1, m);
        a2 += __shfl_xor(a2, m);
        a3 += __shfl_xor(a3, m);
    }
    if (lane == 0) {
        float di = dinv[node];
        *reinterpret_cast<float4*>(hs + (size_t)node * 4) =
            make_float4(a0 * di, a1 * di, a2 * di, a3 * di);
    }
}

// Fused layer (4-wide hs): LDS-bucket aggregate + finalize + next matmul.
// h = tanh((agg + hs[node])*dinv + b); hsn = (h @ Wn) * dinv.
template <int FOUT>
__global__ void k_layer4(const int* __restrict__ bstart, const int* __restrict__ packed,
                         const float* __restrict__ hs, const float* __restrict__ dinv,
                         const float* __restrict__ b_, const float* __restrict__ Wn,
                         float* __restrict__ hsn, int n) {
    __shared__ float agg[1024];
    int b = blockIdx.x;
    int tid = threadIdx.x;
    for (int k = tid; k < 1024; k += 512) agg[k] = 0.0f;
    __syncthreads();
    int j0 = bstart[b], j1 = bstart[b + 1];
    for (int j = j0 + tid; j < j1; j += 512) {
        int w = packed[j];
        int s = w & 0x1FFFF;
        int dl = w >> 17;
        float4 v = *reinterpret_cast<const float4*>(hs + (size_t)s * 4);
        atomicAdd(&agg[dl * 4 + 0], v.x);
        atomicAdd(&agg[dl * 4 + 1], v.y);
        atomicAdd(&agg[dl * 4 + 2], v.z);
        atomicAdd(&agg[dl * 4 + 3], v.w);
    }
    __syncthreads();
    int node = (b << 8) + tid;
    if (tid >= 256 || node >= n) return;
    float4 sv = *reinterpret_cast<const float4*>(hs + (size_t)node * 4);
    float di = dinv[node];
    float h0 = tanhf((agg[tid * 4 + 0] + sv.x) * di + b_[0]);
    float h1 = tanhf((agg[tid * 4 + 1] + sv.y) * di + b_[1]);
    float h2 = tanhf((agg[tid * 4 + 2] + sv.z) * di + b_[2]);
    float h3 = tanhf((agg[tid * 4 + 3] + sv.w) * di + b_[3]);
    float o[FOUT];
#pragma unroll
    for (int j = 0; j < FOUT; j++) {
        o[j] = (h0 * Wn[0 * FOUT + j] + h1 * Wn[1 * FOUT + j] +
                h2 * Wn[2 * FOUT + j] + h3 * Wn[3 * FOUT + j]) * di;
    }
    if constexpr (FOUT == 4) {
        *reinterpret_cast<float4*>(hsn + (size_t)node * 4) =
            make_float4(o[0], o[1], o[2], o[3]);
    } else {
        *reinterpret_cast<float2*>(hsn + (size_t)node * 2) = make_float2(o[0], o[1]);
    }
}

// Final fused layer (2-wide hs): aggregate + tanh -> hout; out = h@Wc + bc.
__global__ void k_layer3(const int* __restrict__ bstart, const int* __restrict__ packed,
                         const float* __restrict__ hs, const float* __restrict__ dinv,
                         const float* __restrict__ b3, const float* __restrict__ Wc,
                         const float* __restrict__ bc, float* __restrict__ out,
                         float* __restrict__ hout, int n) {
    __shared__ float agg[512];
    int b = blockIdx.x;
    int tid = threadIdx.x;
    agg[tid] = 0.0f;
    __syncthreads();
    int j0 = bstart[b], j1 = bstart[b + 1];
    for (int j = j0 + tid; j < j1; j += 512) {
        int w = packed[j];
        int s = w & 0x1FFFF;
        int dl = w >> 17;
        float2 v = *reinterpret_cast<const float2*>(hs + (size_t)s * 2);
        atomicAdd(&agg[dl * 2 + 0], v.x);
        atomicAdd(&agg[dl * 2 + 1], v.y);
    }
    __syncthreads();
    int node = (b << 8) + tid;
    if (tid >= 256 || node >= n) return;
    float2 sv = *reinterpret_cast<const float2*>(hs + (size_t)node * 2);
    float di = dinv[node];
    float h0 = tanhf((agg[tid * 2 + 0] + sv.x) * di + b3[0]);
    float h1 = tanhf((agg[tid * 2 + 1] + sv.y) * di + b3[1]);
    *reinterpret_cast<float2*>(hout + (size_t)node * 2) = make_float2(h0, h1);
    float4 o;
    o.x = h0 * Wc[0] + h1 * Wc[4] + bc[0];
    o.y = h0 * Wc[1] + h1 * Wc[5] + bc[1];
    o.z = h0 * Wc[2] + h1 * Wc[6] + bc[2];
    o.w = h0 * Wc[3] + h1 * Wc[7] + bc[3];
    *reinterpret_cast<float4*>(out + (size_t)node * 4) = o;
}

extern "C" void kernel_launch(void* const* d_in, const int* in_sizes, int n_in,
                              void* d_out, int out_size, void* d_ws, size_t ws_size,
                              hipStream_t stream) {
    const float* x  = (const float*)d_in[0];
    const int*  ei  = (const int*)d_in[1];
    const float* W1 = (const float*)d_in[2];
    const float* b1 = (const float*)d_in[3];
    const float* W2 = (const float*)d_in[4];
    const float* b2 = (const float*)d_in[5];
    const float* W3 = (const float*)d_in[6];
    const float* b3 = (const float*)d_in[7];
    const float* Wc = (const float*)d_in[8];
    const float* bc = (const float*)d_in[9];

    const int n = in_sizes[0] / 128;
    const int e = in_sizes[1] / 2;
    const int* src = ei;
    const int* dst = ei + e;

    const int NB = (n + 255) >> 8;            // dst buckets (256 nodes each)
    const int G  = (e + CHUNK - 1) / CHUNK;   // edge chunks

    const size_t MB = 1024 * 1024;
    char* ws = (char*)d_ws;
    float* dinv   = (float*)(ws + 0 * MB);    // n floats
    float* hsA    = (float*)(ws + 1 * MB);    // n*4 floats
    float* hsB    = (float*)(ws + 3 * MB);    // n*4 floats
    int*   hbase  = (int*)  (ws + 5 * MB);    // G*NB ints (~1.3 MB)
    int*   bstart = (int*)  (ws + 7 * MB);    // NB+1 ints
    int*   packed = (int*)  (ws + 8 * MB);    // e ints (25.6 MB)

    float* out  = (float*)d_out;
    float* hout = out + (size_t)n * 4;

    // Build bucketed edge list (once; reused by all 3 layers)
    k_hist<<<G, 256, 0, stream>>>(dst, hbase, NB, e);
    k_scan2<<<1, 512, 0, stream>>>(hbase, bstart, G, NB, e);
    k_part<<<G, 256, 0, stream>>>(src, dst, hbase, packed, NB, e);
    k_deg2<<<NB, 512, 0, stream>>>(bstart, packed, dinv, n);

    // Layer 1 GEMV: hsA = (x @ W1) * dinv
    k_mm1<<<(n + 3) / 4, 256, 0, stream>>>(x, W1, dinv, hsA, n);

    // Fused aggregate+finalize layers
    k_layer4<4><<<NB, 512, 0, stream>>>(bstart, packed, hsA, dinv, b1, W2, hsB, n);
    k_layer4<2><<<NB, 512, 0, stream>>>(bstart, packed, hsB, dinv, b2, W3, hsA, n);
    k_layer3<<<NB, 512, 0, stream>>>(bstart, packed, hsA, dinv, b3, Wc, bc, out, hout, n);

    (void)n_in; (void)out_size; (void)ws_size;
}

// Round 4
// 554.303 us; speedup vs baseline: 6.2174x; 1.5017x over previous
//
#include <hip/hip_runtime.h>
#include <math.h>

// GCN forward: 3x GCNConv (128->4->4->2) + classifier (2->4).
// Edges partitioned once per call into 256-node dst-buckets (packed int:
// dl<<17|src). Per-layer aggregation = LDS-privatized atomicAdd per bucket,
// fused with finalize (tanh + next-layer matmul). Zero global atomics.
// Histogram stored bucket-major (hbT[b][g]) so the offset scan is a
// parallel per-bucket row scan instead of a single-block serial pass.

#define CHUNK 8192

// Pass A: per-block histogram of dst-buckets (bucket = dst>>8), transposed.
__global__ void k_hist(const int* __restrict__ dst, int* __restrict__ hbT,
                       int NB, int G, int e) {
    __shared__ int hist[512];
    int g = blockIdx.x;
    for (int b = threadIdx.x; b < NB; b += 256) hist[b] = 0;
    __syncthreads();
    int i0 = g * CHUNK, i1 = min(i0 + CHUNK, e);
    for (int i = i0 + threadIdx.x; i < i1; i += 256)
        atomicAdd(&hist[dst[i] >> 8], 1);
    __syncthreads();
    for (int b = threadIdx.x; b < NB; b += 256)
        hbT[(size_t)b * G + g] = hist[b];
}

// Scan A: one block per bucket; exclusive scan of hbT[b][0..G) in place
// (coalesced row), bucket total -> btot[b].
__global__ void k_scanA(int* __restrict__ hbT, int* __restrict__ btot, int G) {
    __shared__ int part[256];
    int b = blockIdx.x;
    int t = threadIdx.x;
    int* row = hbT + (size_t)b * G;
    int C = (G + 255) / 256;
    int lo = t * C, hi = min(lo + C, G);
    int s = 0;
    for (int i = lo; i < hi; i++) s += row[i];
    part[t] = s;
    __syncthreads();
#pragma unroll
    for (int off = 1; off < 256; off <<= 1) {
        int u = (t >= off) ? part[t - off] : 0;
        __syncthreads();
        part[t] += u;
        __syncthreads();
    }
    int run = part[t] - s;  // exclusive base for this thread's chunk
    for (int i = lo; i < hi; i++) {
        int v = row[i];
        row[i] = run;
        run += v;
    }
    if (t == 255) btot[b] = part[255];
}

// Scan B: exclusive scan of the NB bucket totals (NB <= 512).
__global__ void k_scanB(const int* __restrict__ btot, int* __restrict__ bstart,
                        int NB, int e) {
    __shared__ int part[512];
    int t = threadIdx.x;
    int v = (t < NB) ? btot[t] : 0;
    part[t] = v;
    __syncthreads();
#pragma unroll
    for (int off = 1; off < 512; off <<= 1) {
        int u = (t >= off) ? part[t - off] : 0;
        __syncthreads();
        part[t] += u;
        __syncthreads();
    }
    if (t < NB) bstart[t] = part[t] - v;
    if (t == 0) bstart[NB] = e;
}

// Pass B: partition edges into buckets. Per-(block,bucket) private contiguous
// runs -> full cache lines, no global atomics. packed = (dst&255)<<17 | src.
__global__ void k_part(const int* __restrict__ src, const int* __restrict__ dst,
                       const int* __restrict__ hbT, const int* __restrict__ bstart,
                       int* __restrict__ packed, int NB, int G, int e) {
    __shared__ int cur[512];
    int g = blockIdx.x;
    for (int b = threadIdx.x; b < NB; b += 256)
        cur[b] = hbT[(size_t)b * G + g] + bstart[b];
    __syncthreads();
    int i0 = g * CHUNK, i1 = min(i0 + CHUNK, e);
    for (int i = i0 + threadIdx.x; i < i1; i += 256) {
        int d = dst[i];
        int s = src[i];
        int pos = atomicAdd(&cur[d >> 8], 1);
        packed[pos] = ((d & 255) << 17) | s;
    }
}

// Per-bucket degree histogram -> dinv (deg + 1 self-loop).
__global__ void k_deg2(const int* __restrict__ bstart, const int* __restrict__ packed,
                       float* __restrict__ dinv, int n) {
    __shared__ int cnt[256];
    int b = blockIdx.x;
    int tid = threadIdx.x;
    if (tid < 256) cnt[tid] = 0;
    __syncthreads();
    int j0 = bstart[b], j1 = bstart[b + 1];
    for (int j = j0 + tid; j < j1; j += 512)
        atomicAdd(&cnt[packed[j] >> 17], 1);
    __syncthreads();
    int node = (b << 8) + tid;
    if (tid < 256 && node < n)
        dinv[node] = 1.0f / sqrtf((float)(cnt[tid] + 1));
}

// Layer 1 GEMV: one wave per node. hs = (x @ W1) * dinv.
__global__ void k_mm1(const float* __restrict__ x, const float* __restrict__ W,
                      const float* __restrict__ dinv, float* __restrict__ hs, int n) {
    int gid = blockIdx.x * blockDim.x + threadIdx.x;
    int node = gid >> 6;
    int lane = threadIdx.x & 63;
    if (node >= n) return;
    const float2 xv = *reinterpret_cast<const float2*>(x + (size_t)node * 128 + lane * 2);
    const float4 w0 = *reinterpret_cast<const float4*>(W + (lane * 2) * 4);
    const float4 w1 = *reinterpret_cast<const float4*>(W + (lane * 2 + 1) * 4);
    float a0 = xv.x * w0.x + xv.y * w1.x;
    float a1 = xv.x * w0.y + xv.y * w1.y;
    float a2 = xv.x * w0.z + xv.y * w1.z;
    float a3 = xv.x * w0.w + xv.y * w1.w;
#pragma unroll
    for (int m = 32; m >= 1; m >>= 1) {
        a0 += __shfl_xor(a0, m);
        a1 += __shfl_xor(a1, m);
        a2 += __shfl_xor(a2, m);
        a3 += __shfl_xor(a3, m);
    }
    if (lane == 0) {
        float di = dinv[node];
        *reinterpret_cast<float4*>(hs + (size_t)node * 4) =
            make_float4(a0 * di, a1 * di, a2 * di, a3 * di);
    }
}

// Fused layer (4-wide hs): LDS-bucket aggregate + finalize + next matmul.
template <int FOUT>
__global__ void k_layer4(const int* __restrict__ bstart, const int* __restrict__ packed,
                         const float* __restrict__ hs, const float* __restrict__ dinv,
                         const float* __restrict__ b_, const float* __restrict__ Wn,
                         float* __restrict__ hsn, int n) {
    __shared__ float agg[1024];
    int b = blockIdx.x;
    int tid = threadIdx.x;
    for (int k = tid; k < 1024; k += 512) agg[k] = 0.0f;
    __syncthreads();
    int j0 = bstart[b], j1 = bstart[b + 1];
    for (int j = j0 + tid; j < j1; j += 512) {
        int w = packed[j];
        int s = w & 0x1FFFF;
        int dl = w >> 17;
        float4 v = *reinterpret_cast<const float4*>(hs + (size_t)s * 4);
        atomicAdd(&agg[dl * 4 + 0], v.x);
        atomicAdd(&agg[dl * 4 + 1], v.y);
        atomicAdd(&agg[dl * 4 + 2], v.z);
        atomicAdd(&agg[dl * 4 + 3], v.w);
    }
    __syncthreads();
    int node = (b << 8) + tid;
    if (tid >= 256 || node >= n) return;
    float4 sv = *reinterpret_cast<const float4*>(hs + (size_t)node * 4);
    float di = dinv[node];
    float h0 = tanhf((agg[tid * 4 + 0] + sv.x) * di + b_[0]);
    float h1 = tanhf((agg[tid * 4 + 1] + sv.y) * di + b_[1]);
    float h2 = tanhf((agg[tid * 4 + 2] + sv.z) * di + b_[2]);
    float h3 = tanhf((agg[tid * 4 + 3] + sv.w) * di + b_[3]);
    float o[FOUT];
#pragma unroll
    for (int j = 0; j < FOUT; j++) {
        o[j] = (h0 * Wn[0 * FOUT + j] + h1 * Wn[1 * FOUT + j] +
                h2 * Wn[2 * FOUT + j] + h3 * Wn[3 * FOUT + j]) * di;
    }
    if constexpr (FOUT == 4) {
        *reinterpret_cast<float4*>(hsn + (size_t)node * 4) =
            make_float4(o[0], o[1], o[2], o[3]);
    } else {
        *reinterpret_cast<float2*>(hsn + (size_t)node * 2) = make_float2(o[0], o[1]);
    }
}

// Final fused layer (2-wide hs): aggregate + tanh -> hout; out = h@Wc + bc.
__global__ void k_layer3(const int* __restrict__ bstart, const int* __restrict__ packed,
                         const float* __restrict__ hs, const float* __restrict__ dinv,
                         const float* __restrict__ b3, const float* __restrict__ Wc,
                         const float* __restrict__ bc, float* __restrict__ out,
                         float* __restrict__ hout, int n) {
    __shared__ float agg[512];
    int b = blockIdx.x;
    int tid = threadIdx.x;
    agg[tid] = 0.0f;
    __syncthreads();
    int j0 = bstart[b], j1 = bstart[b + 1];
    for (int j = j0 + tid; j < j1; j += 512) {
        int w = packed[j];
        int s = w & 0x1FFFF;
        int dl = w >> 17;
        float2 v = *reinterpret_cast<const float2*>(hs + (size_t)s * 2);
        atomicAdd(&agg[dl * 2 + 0], v.x);
        atomicAdd(&agg[dl * 2 + 1], v.y);
    }
    __syncthreads();
    int node = (b << 8) + tid;
    if (tid >= 256 || node >= n) return;
    float2 sv = *reinterpret_cast<const float2*>(hs + (size_t)node * 2);
    float di = dinv[node];
    float h0 = tanhf((agg[tid * 2 + 0] + sv.x) * di + b3[0]);
    float h1 = tanhf((agg[tid * 2 + 1] + sv.y) * di + b3[1]);
    *reinterpret_cast<float2*>(hout + (size_t)node * 2) = make_float2(h0, h1);
    float4 o;
    o.x = h0 * Wc[0] + h1 * Wc[4] + bc[0];
    o.y = h0 * Wc[1] + h1 * Wc[5] + bc[1];
    o.z = h0 * Wc[2] + h1 * Wc[6] + bc[2];
    o.w = h0 * Wc[3] + h1 * Wc[7] + bc[3];
    *reinterpret_cast<float4*>(out + (size_t)node * 4) = o;
}

extern "C" void kernel_launch(void* const* d_in, const int* in_sizes, int n_in,
                              void* d_out, int out_size, void* d_ws, size_t ws_size,
                              hipStream_t stream) {
    const float* x  = (const float*)d_in[0];
    const int*  ei  = (const int*)d_in[1];
    const float* W1 = (const float*)d_in[2];
    const float* b1 = (const float*)d_in[3];
    const float* W2 = (const float*)d_in[4];
    const float* b2 = (const float*)d_in[5];
    const float* W3 = (const float*)d_in[6];
    const float* b3 = (const float*)d_in[7];
    const float* Wc = (const float*)d_in[8];
    const float* bc = (const float*)d_in[9];

    const int n = in_sizes[0] / 128;
    const int e = in_sizes[1] / 2;
    const int* src = ei;
    const int* dst = ei + e;

    const int NB = (n + 255) >> 8;            // dst buckets (256 nodes each)
    const int G  = (e + CHUNK - 1) / CHUNK;   // edge chunks

    const size_t MB = 1024 * 1024;
    char* ws = (char*)d_ws;
    float* dinv   = (float*)(ws + 0 * MB);    // n floats
    float* hsA    = (float*)(ws + 1 * MB);    // n*4 floats
    float* hsB    = (float*)(ws + 3 * MB);    // n*4 floats
    int*   hbT    = (int*)  (ws + 5 * MB);    // NB*G ints (~1.3 MB), bucket-major
    int*   btot   = (int*)  (ws + 7 * MB);    // NB ints
    int*   bstart = (int*)  (ws + 7 * MB + 4096); // NB+1 ints
    int*   packed = (int*)  (ws + 8 * MB);    // e ints (25.6 MB)

    float* out  = (float*)d_out;
    float* hout = out + (size_t)n * 4;

    // Build bucketed edge list (once; reused by all 3 layers)
    k_hist<<<G, 256, 0, stream>>>(dst, hbT, NB, G, e);
    k_scanA<<<NB, 256, 0, stream>>>(hbT, btot, G);
    k_scanB<<<1, 512, 0, stream>>>(btot, bstart, NB, e);
    k_part<<<G, 256, 0, stream>>>(src, dst, hbT, bstart, packed, NB, G, e);
    k_deg2<<<NB, 512, 0, stream>>>(bstart, packed, dinv, n);

    // Layer 1 GEMV: hsA = (x @ W1) * dinv
    k_mm1<<<(n + 3) / 4, 256, 0, stream>>>(x, W1, dinv, hsA, n);

    // Fused aggregate+finalize layers
    k_layer4<4><<<NB, 512, 0, stream>>>(bstart, packed, hsA, dinv, b1, W2, hsB, n);
    k_layer4<2><<<NB, 512, 0, stream>>>(bstart, packed, hsB, dinv, b2, W3, hsA, n);
    k_layer3<<<NB, 512, 0, stream>>>(bstart, packed, hsA, dinv, b3, Wc, bc, out, hout, n);

    (void)n_in; (void)out_size; (void)ws_size;
}

// Round 5
// 489.896 us; speedup vs baseline: 7.0348x; 1.1315x over previous
//
#include <hip/hip_runtime.h>
#include <math.h>

// GCN forward: 3x GCNConv (128->4->4->2) + classifier (2->4).
// Edges partitioned once per call into 256-node dst-buckets (packed int:
// dl<<17|src). Per-layer aggregation: NB*SEG blocks each aggregate a bucket
// SEGMENT into LDS (transposed, padded -> conflict-free), write compact
// partials; combine kernel sums partials + fused finalize (tanh + next
// matmul). Zero global atomics; high occupancy everywhere.

#define CHUNK 8192

// Pass A: per-block histogram of dst-buckets (bucket = dst>>8), transposed.
__global__ void k_hist(const int* __restrict__ dst, int* __restrict__ hbT,
                       int NB, int G, int e) {
    __shared__ int hist[512];
    int g = blockIdx.x;
    for (int b = threadIdx.x; b < NB; b += 256) hist[b] = 0;
    __syncthreads();
    int i0 = g * CHUNK, i1 = min(i0 + CHUNK, e);
    for (int i = i0 + threadIdx.x; i < i1; i += 256)
        atomicAdd(&hist[dst[i] >> 8], 1);
    __syncthreads();
    for (int b = threadIdx.x; b < NB; b += 256)
        hbT[(size_t)b * G + g] = hist[b];
}

// Scan A: one block per bucket; exclusive scan of hbT[b][0..G) in place.
__global__ void k_scanA(int* __restrict__ hbT, int* __restrict__ btot, int G) {
    __shared__ int part[256];
    int b = blockIdx.x;
    int t = threadIdx.x;
    int* row = hbT + (size_t)b * G;
    int C = (G + 255) / 256;
    int lo = t * C, hi = min(lo + C, G);
    int s = 0;
    for (int i = lo; i < hi; i++) s += row[i];
    part[t] = s;
    __syncthreads();
#pragma unroll
    for (int off = 1; off < 256; off <<= 1) {
        int u = (t >= off) ? part[t - off] : 0;
        __syncthreads();
        part[t] += u;
        __syncthreads();
    }
    int run = part[t] - s;
    for (int i = lo; i < hi; i++) {
        int v = row[i];
        row[i] = run;
        run += v;
    }
    if (t == 255) btot[b] = part[255];
}

// Scan B: exclusive scan of the NB bucket totals (NB <= 512).
__global__ void k_scanB(const int* __restrict__ btot, int* __restrict__ bstart,
                        int NB, int e) {
    __shared__ int part[512];
    int t = threadIdx.x;
    int v = (t < NB) ? btot[t] : 0;
    part[t] = v;
    __syncthreads();
#pragma unroll
    for (int off = 1; off < 512; off <<= 1) {
        int u = (t >= off) ? part[t - off] : 0;
        __syncthreads();
        part[t] += u;
        __syncthreads();
    }
    if (t < NB) bstart[t] = part[t] - v;
    if (t == 0) bstart[NB] = e;
}

// Pass B: partition edges into buckets. packed = (dst&255)<<17 | src.
__global__ void k_part(const int* __restrict__ src, const int* __restrict__ dst,
                       const int* __restrict__ hbT, const int* __restrict__ bstart,
                       int* __restrict__ packed, int NB, int G, int e) {
    __shared__ int cur[512];
    int g = blockIdx.x;
    for (int b = threadIdx.x; b < NB; b += 256)
        cur[b] = hbT[(size_t)b * G + g] + bstart[b];
    __syncthreads();
    int i0 = g * CHUNK, i1 = min(i0 + CHUNK, e);
    for (int i = i0 + threadIdx.x; i < i1; i += 256) {
        int d = dst[i];
        int s = src[i];
        int pos = atomicAdd(&cur[d >> 8], 1);
        packed[pos] = ((d & 255) << 17) | s;
    }
}

// Segmented degree histogram: partial counts per (bucket,segment) block.
__global__ void k_degseg(const int* __restrict__ bstart, const int* __restrict__ packed,
                         int* __restrict__ pdeg, int SEG) {
    __shared__ int cnt[256];
    int blk = blockIdx.x;
    int b = blk / SEG, s = blk - b * SEG;
    int tid = threadIdx.x;
    cnt[tid] = 0;
    __syncthreads();
    int j0 = bstart[b], len = bstart[b + 1] - j0;
    int lo = j0 + (int)((long long)len * s / SEG);
    int hi = j0 + (int)((long long)len * (s + 1) / SEG);
    for (int j = lo + tid; j < hi; j += 256)
        atomicAdd(&cnt[packed[j] >> 17], 1);
    __syncthreads();
    pdeg[(size_t)blk * 256 + tid] = cnt[tid];
}

__global__ void k_degcomb(const int* __restrict__ pdeg, float* __restrict__ dinv,
                          int n, int SEG) {
    int b = blockIdx.x, tid = threadIdx.x;
    int node = (b << 8) + tid;
    if (node >= n) return;
    const int* P = pdeg + (size_t)b * SEG * 256 + tid;
    int c = 0;
    for (int s = 0; s < SEG; s++) c += P[s * 256];
    dinv[node] = 1.0f / sqrtf((float)(c + 1));
}

// Layer 1 GEMV: one wave per node. hs = (x @ W1) * dinv.
__global__ void k_mm1(const float* __restrict__ x, const float* __restrict__ W,
                      const float* __restrict__ dinv, float* __restrict__ hs, int n) {
    int gid = blockIdx.x * blockDim.x + threadIdx.x;
    int node = gid >> 6;
    int lane = threadIdx.x & 63;
    if (node >= n) return;
    const float2 xv = *reinterpret_cast<const float2*>(x + (size_t)node * 128 + lane * 2);
    const float4 w0 = *reinterpret_cast<const float4*>(W + (lane * 2) * 4);
    const float4 w1 = *reinterpret_cast<const float4*>(W + (lane * 2 + 1) * 4);
    float a0 = xv.x * w0.x + xv.y * w1.x;
    float a1 = xv.x * w0.y + xv.y * w1.y;
    float a2 = xv.x * w0.z + xv.y * w1.z;
    float a3 = xv.x * w0.w + xv.y * w1.w;
#pragma unroll
    for (int m = 32; m >= 1; m >>= 1) {
        a0 += __shfl_xor(a0, m);
        a1 += __shfl_xor(a1, m);
        a2 += __shfl_xor(a2, m);
        a3 += __shfl_xor(a3, m);
    }
    if (lane == 0) {
        float di = dinv[node];
        *reinterpret_cast<float4*>(hs + (size_t)node * 4) =
            make_float4(a0 * di, a1 * di, a2 * di, a3 * di);
    }
}

// Segment aggregate, 4-wide hs. LDS transposed+padded: agg[c][260] -> ~2-way
// (free) bank aliasing instead of 8-way. Compact partial write [4][256].
__global__ void k_seg4(const int* __restrict__ bstart, const int* __restrict__ packed,
                       const float* __restrict__ hs, float* __restrict__ partial,
                       int SEG) {
    __shared__ float agg[4 * 260];
    int blk = blockIdx.x;
    int b = blk / SEG, s = blk - b * SEG;
    int tid = threadIdx.x;
    for (int k = tid; k < 4 * 260; k += 256) agg[k] = 0.0f;
    __syncthreads();
    int j0 = bstart[b], len = bstart[b + 1] - j0;
    int lo = j0 + (int)((long long)len * s / SEG);
    int hi = j0 + (int)((long long)len * (s + 1) / SEG);
    for (int j = lo + tid; j < hi; j += 256) {
        int w = packed[j];
        int sr = w & 0x1FFFF;
        int dl = w >> 17;
        float4 v = *reinterpret_cast<const float4*>(hs + (size_t)sr * 4);
        atomicAdd(&agg[0 * 260 + dl], v.x);
        atomicAdd(&agg[1 * 260 + dl], v.y);
        atomicAdd(&agg[2 * 260 + dl], v.z);
        atomicAdd(&agg[3 * 260 + dl], v.w);
    }
    __syncthreads();
    float* P = partial + (size_t)blk * 1024;
    for (int k = tid; k < 1024; k += 256)
        P[k] = agg[(k >> 8) * 260 + (k & 255)];
}

// Segment aggregate, 2-wide hs.
__global__ void k_seg2(const int* __restrict__ bstart, const int* __restrict__ packed,
                       const float* __restrict__ hs, float* __restrict__ partial,
                       int SEG) {
    __shared__ float agg[2 * 260];
    int blk = blockIdx.x;
    int b = blk / SEG, s = blk - b * SEG;
    int tid = threadIdx.x;
    for (int k = tid; k < 2 * 260; k += 256) agg[k] = 0.0f;
    __syncthreads();
    int j0 = bstart[b], len = bstart[b + 1] - j0;
    int lo = j0 + (int)((long long)len * s / SEG);
    int hi = j0 + (int)((long long)len * (s + 1) / SEG);
    for (int j = lo + tid; j < hi; j += 256) {
        int w = packed[j];
        int sr = w & 0x1FFFF;
        int dl = w >> 17;
        float2 v = *reinterpret_cast<const float2*>(hs + (size_t)sr * 2);
        atomicAdd(&agg[0 * 260 + dl], v.x);
        atomicAdd(&agg[1 * 260 + dl], v.y);
    }
    __syncthreads();
    float* P = partial + (size_t)blk * 512;
    for (int k = tid; k < 512; k += 256)
        P[k] = agg[(k >> 8) * 260 + (k & 255)];
}

// Combine partials + finalize: h = tanh((agg+hs)*dinv + b); hsn = (h@Wn)*dinv.
template <int FOUT>
__global__ void k_comb4(const float* __restrict__ partial, const float* __restrict__ hs,
                        const float* __restrict__ dinv, const float* __restrict__ b_,
                        const float* __restrict__ Wn, float* __restrict__ hsn,
                        int n, int SEG) {
    int b = blockIdx.x, tid = threadIdx.x;
    int node = (b << 8) + tid;
    if (node >= n) return;
    const float* P = partial + (size_t)b * SEG * 1024 + tid;
    float a0 = 0.f, a1 = 0.f, a2 = 0.f, a3 = 0.f;
    for (int s = 0; s < SEG; s++) {
        const float* q = P + s * 1024;
        a0 += q[0]; a1 += q[256]; a2 += q[512]; a3 += q[768];
    }
    float4 sv = *reinterpret_cast<const float4*>(hs + (size_t)node * 4);
    float di = dinv[node];
    float h0 = tanhf((a0 + sv.x) * di + b_[0]);
    float h1 = tanhf((a1 + sv.y) * di + b_[1]);
    float h2 = tanhf((a2 + sv.z) * di + b_[2]);
    float h3 = tanhf((a3 + sv.w) * di + b_[3]);
    float o[FOUT];
#pragma unroll
    for (int j = 0; j < FOUT; j++) {
        o[j] = (h0 * Wn[0 * FOUT + j] + h1 * Wn[1 * FOUT + j] +
                h2 * Wn[2 * FOUT + j] + h3 * Wn[3 * FOUT + j]) * di;
    }
    if constexpr (FOUT == 4) {
        *reinterpret_cast<float4*>(hsn + (size_t)node * 4) =
            make_float4(o[0], o[1], o[2], o[3]);
    } else {
        *reinterpret_cast<float2*>(hsn + (size_t)node * 2) = make_float2(o[0], o[1]);
    }
}

// Final combine: h3 = tanh(...) -> hout; out = h3@Wc + bc.
__global__ void k_comb3(const float* __restrict__ partial, const float* __restrict__ hs,
                        const float* __restrict__ dinv, const float* __restrict__ b3,
                        const float* __restrict__ Wc, const float* __restrict__ bc,
                        float* __restrict__ out, float* __restrict__ hout,
                        int n, int SEG) {
    int b = blockIdx.x, tid = threadIdx.x;
    int node = (b << 8) + tid;
    if (node >= n) return;
    const float* P = partial + (size_t)b * SEG * 512 + tid;
    float a0 = 0.f, a1 = 0.f;
    for (int s = 0; s < SEG; s++) {
        const float* q = P + s * 512;
        a0 += q[0]; a1 += q[256];
    }
    float2 sv = *reinterpret_cast<const float2*>(hs + (size_t)node * 2);
    float di = dinv[node];
    float h0 = tanhf((a0 + sv.x) * di + b3[0]);
    float h1 = tanhf((a1 + sv.y) * di + b3[1]);
    *reinterpret_cast<float2*>(hout + (size_t)node * 2) = make_float2(h0, h1);
    float4 o;
    o.x = h0 * Wc[0] + h1 * Wc[4] + bc[0];
    o.y = h0 * Wc[1] + h1 * Wc[5] + bc[1];
    o.z = h0 * Wc[2] + h1 * Wc[6] + bc[2];
    o.w = h0 * Wc[3] + h1 * Wc[7] + bc[3];
    *reinterpret_cast<float4*>(out + (size_t)node * 4) = o;
}

extern "C" void kernel_launch(void* const* d_in, const int* in_sizes, int n_in,
                              void* d_out, int out_size, void* d_ws, size_t ws_size,
                              hipStream_t stream) {
    const float* x  = (const float*)d_in[0];
    const int*  ei  = (const int*)d_in[1];
    const float* W1 = (const float*)d_in[2];
    const float* b1 = (const float*)d_in[3];
    const float* W2 = (const float*)d_in[4];
    const float* b2 = (const float*)d_in[5];
    const float* W3 = (const float*)d_in[6];
    const float* b3 = (const float*)d_in[7];
    const float* Wc = (const float*)d_in[8];
    const float* bc = (const float*)d_in[9];

    const int n = in_sizes[0] / 128;
    const int e = in_sizes[1] / 2;
    const int* src = ei;
    const int* dst = ei + e;

    const int NB = (n + 255) >> 8;            // dst buckets (256 nodes each)
    const int G  = (e + CHUNK - 1) / CHUNK;   // edge chunks

    const size_t MB = 1024 * 1024;
    char* ws = (char*)d_ws;
    float* dinv    = (float*)(ws + 0 * MB);   // n floats
    float* hsA     = (float*)(ws + 1 * MB);   // n*4 floats
    float* hsB     = (float*)(ws + 3 * MB);   // n*4 floats
    int*   hbT     = (int*)  (ws + 5 * MB);   // NB*G ints (~1.3 MB)
    int*   btot    = (int*)  (ws + 7 * MB);   // NB ints
    int*   bstart  = (int*)  (ws + 7 * MB + 4096);
    int*   packed  = (int*)  (ws + 8 * MB);   // e ints (25.6 MB)
    float* partial = (float*)(ws + 34 * MB);  // SEG*NB*1024 floats

    // pick SEG so the partial buffer fits the workspace
    int SEG = 8;
    while (SEG > 1 && 34 * MB + (size_t)SEG * NB * 1024 * 4 > ws_size) SEG >>= 1;

    float* out  = (float*)d_out;
    float* hout = out + (size_t)n * 4;

    // Build bucketed edge list (once; reused by all 3 layers)
    k_hist<<<G, 256, 0, stream>>>(dst, hbT, NB, G, e);
    k_scanA<<<NB, 256, 0, stream>>>(hbT, btot, G);
    k_scanB<<<1, 512, 0, stream>>>(btot, bstart, NB, e);
    k_part<<<G, 256, 0, stream>>>(src, dst, hbT, bstart, packed, NB, G, e);

    // degree -> dinv (segmented)
    k_degseg<<<NB * SEG, 256, 0, stream>>>(bstart, packed, (int*)partial, SEG);
    k_degcomb<<<NB, 256, 0, stream>>>((const int*)partial, dinv, n, SEG);

    // Layer 1 GEMV: hsA = (x @ W1) * dinv
    k_mm1<<<(n + 3) / 4, 256, 0, stream>>>(x, W1, dinv, hsA, n);

    // Layer 1: aggregate + finalize (fused W2)
    k_seg4<<<NB * SEG, 256, 0, stream>>>(bstart, packed, hsA, partial, SEG);
    k_comb4<4><<<NB, 256, 0, stream>>>(partial, hsA, dinv, b1, W2, hsB, n, SEG);
    // Layer 2: aggregate + finalize (fused W3)
    k_seg4<<<NB * SEG, 256, 0, stream>>>(bstart, packed, hsB, partial, SEG);
    k_comb4<2><<<NB, 256, 0, stream>>>(partial, hsB, dinv, b2, W3, hsA, n, SEG);
    // Layer 3: aggregate + finalize (fused classifier)
    k_seg2<<<NB * SEG, 256, 0, stream>>>(bstart, packed, hsA, partial, SEG);
    k_comb3<<<NB, 256, 0, stream>>>(partial, hsA, dinv, b3, Wc, bc, out, hout, n, SEG);

    (void)n_in; (void)out_size; (void)ws_size;
}